// Round 5
// baseline (557.248 us; speedup 1.0000x reference)
//
#include <hip/hip_runtime.h>
#include <hip/hip_bf16.h>
#include <math.h>

typedef __bf16 bf16_t;
typedef __bf16 bf16x4 __attribute__((ext_vector_type(4)));
typedef short  s16x8  __attribute__((ext_vector_type(8)));
typedef float  f32x4  __attribute__((ext_vector_type(4)));

#define DEVINL __device__ __forceinline__

DEVINL void gload_lds16(const void* g, void* l) {
  __builtin_amdgcn_global_load_lds(
      (const __attribute__((address_space(1))) unsigned int*)g,
      (__attribute__((address_space(3))) unsigned int*)l, 16, 0, 0);
}

DEVINL f32x4 mfma16(s16x8 a, s16x8 b, f32x4 c) {
  return __builtin_amdgcn_mfma_f32_16x16x32_bf16(a, b, c, 0, 0, 0);
}

// ---------------- transpose + cast: W[K][N] f32 -> WT[N][K] bf16 ----------------
__global__ __launch_bounds__(256) void tcast_kernel(const float* __restrict__ W,
                                                    bf16_t* __restrict__ WT,
                                                    int K, int N) {
  __shared__ float tile[32][33];
  const int n0 = blockIdx.x * 32, k0 = blockIdx.y * 32;
  const int tx = threadIdx.x, ty = threadIdx.y;
#pragma unroll
  for (int j = 0; j < 4; ++j)
    tile[ty + j * 8][tx] = W[(size_t)(k0 + ty + j * 8) * N + (n0 + tx)];
  __syncthreads();
#pragma unroll
  for (int j = 0; j < 4; ++j)
    WT[(size_t)(n0 + ty + j * 8) * K + (k0 + tx)] = (bf16_t)tile[tx][ty + j * 8];
}

// ---------------- layernorm: f32 [rows][1024] -> bf16 ----------------
__global__ __launch_bounds__(256) void ln_kernel(const float* __restrict__ x,
                                                 const float* __restrict__ w,
                                                 const float* __restrict__ b,
                                                 bf16_t* __restrict__ out) {
  const int row = blockIdx.x, tid = threadIdx.x;
  const float4 v = ((const float4*)(x + (size_t)row * 1024))[tid];
  float s  = v.x + v.y + v.z + v.w;
  float s2 = v.x * v.x + v.y * v.y + v.z * v.z + v.w * v.w;
#pragma unroll
  for (int off = 32; off > 0; off >>= 1) {
    s  += __shfl_down(s, off);
    s2 += __shfl_down(s2, off);
  }
  __shared__ float red[8];
  const int wave = tid >> 6, lane = tid & 63;
  if (lane == 0) { red[wave] = s; red[4 + wave] = s2; }
  __syncthreads();
  s  = red[0] + red[1] + red[2] + red[3];
  s2 = red[4] + red[5] + red[6] + red[7];
  const float mu = s * (1.0f / 1024.0f);
  const float rs = rsqrtf(s2 * (1.0f / 1024.0f) - mu * mu + 1e-5f);
  const float4 wv = ((const float4*)w)[tid];
  const float4 bv = ((const float4*)b)[tid];
  bf16x4 o;
  o[0] = (bf16_t)((v.x - mu) * rs * wv.x + bv.x);
  o[1] = (bf16_t)((v.y - mu) * rs * wv.y + bv.y);
  o[2] = (bf16_t)((v.z - mu) * rs * wv.z + bv.z);
  o[3] = (bf16_t)((v.w - mu) * rs * wv.w + bv.w);
  ((bf16x4*)(out + (size_t)row * 1024))[tid] = o;
}

// ---------------- 256x256 deep-pipelined GEMM ----------------
// C[M][N] = A[M][K] (bf16) * BT[N][K]^T (bf16) + epi
// 8 waves (2M x 4N), BK=64, double-buffered 128 KiB LDS, XOR-swizzled (T2),
// stage-ahead-1-tile with boundary-only vmcnt (elapsed-time latency hiding),
// raw s_barrier phases + setprio MFMA clusters (T5).
// EPI 0: +bias -> bf16 out
// EPI 1: +bias +resid(f32) -> f32 out
// EPI 2: gelu(+bias) -> bf16 out
// EPI 3: qkv split: col<2048 -> bf16 out[M][2048]; col>=2048 -> V^T out2[b][h][d][2048]
template <int EPI>
__global__ __launch_bounds__(512, 2) void gemm256(const bf16_t* __restrict__ A,
                                                  const bf16_t* __restrict__ BT,
                                                  const float* __restrict__ bias,
                                                  const float* __restrict__ resid,
                                                  void* __restrict__ out,
                                                  void* __restrict__ out2,
                                                  int M, int N, int K) {
  __shared__ __align__(16) bf16_t sh[65536];  // 128 KiB: [2][A 16K elems | B 16K elems]
  const int tid = threadIdx.x;
  const int lane = tid & 63, wave = tid >> 6;
  const int wr = wave >> 2, wn = wave & 3;      // 2M x 4N wave grid
  const int g = lane >> 4, lr = lane & 15;

  // bijective XCD swizzle (grids are multiples of 8); M/256 = 32 always
  const int nwg = gridDim.x;
  const int bid = blockIdx.x;
  const int swz = (bid & 7) * (nwg >> 3) + (bid >> 3);
  const int m0 = (swz & 31) * 256, n0 = (swz >> 5) * 256;
  const bf16_t* Ag = A + (size_t)m0 * K;
  const bf16_t* Bg = BT + (size_t)n0 * K;

  f32x4 acc[8][4] = {};
  const int NT = K >> 6;

  // prologue: stage tile 0 into buf0 (linear dest, inverse-swizzled source)
  {
    bf16_t* dA = sh;
    bf16_t* dB = sh + 16384;
#pragma unroll
    for (int q = 0; q < 4; ++q) {
      const int id = q * 512 + tid;
      const int row = id >> 3;
      const int sc = (id & 7) ^ (row & 7);
      const size_t wb = (size_t)(q * 512 + wave * 64) * 8;
      gload_lds16(Ag + (size_t)row * K + sc * 8, dA + wb);
      gload_lds16(Bg + (size_t)row * K + sc * 8, dB + wb);
    }
  }
  asm volatile("s_waitcnt vmcnt(0)" ::: "memory");
  __builtin_amdgcn_s_barrier();

  for (int t = 0; t < NT; ++t) {
    const bf16_t* cA = sh + (t & 1) * 32768;
    const bf16_t* cB = cA + 16384;
    // stage tile t+1 into the other buffer (its readers finished a tile ago)
    if (t + 1 < NT) {
      const int kt = (t + 1) << 6;
      bf16_t* dA = sh + ((t + 1) & 1) * 32768;
      bf16_t* dB = dA + 16384;
#pragma unroll
      for (int q = 0; q < 4; ++q) {
        const int id = q * 512 + tid;
        const int row = id >> 3;
        const int sc = (id & 7) ^ (row & 7);
        const size_t wb = (size_t)(q * 512 + wave * 64) * 8;
        gload_lds16(Ag + (size_t)row * K + kt + sc * 8, dA + wb);
        gload_lds16(Bg + (size_t)row * K + kt + sc * 8, dB + wb);
      }
    }
    s16x8 afr[4], bfr[4];
#pragma unroll
    for (int ks = 0; ks < 2; ++ks) {
      // ---- phase A: m0-3, reload B for this k-step ----
#pragma unroll
      for (int n = 0; n < 4; ++n) {
        const int r = wn * 64 + n * 16 + lr;
        bfr[n] = *(const s16x8*)(cB + (size_t)r * 64 + (size_t)(((ks << 2) + g) ^ (r & 7)) * 8);
      }
#pragma unroll
      for (int m = 0; m < 4; ++m) {
        const int r = wr * 128 + m * 16 + lr;
        afr[m] = *(const s16x8*)(cA + (size_t)r * 64 + (size_t)(((ks << 2) + g) ^ (r & 7)) * 8);
      }
      __builtin_amdgcn_s_setprio(1);
#pragma unroll
      for (int m = 0; m < 4; ++m)
#pragma unroll
        for (int n = 0; n < 4; ++n)
          acc[m][n] = mfma16(afr[m], bfr[n], acc[m][n]);
      __builtin_amdgcn_s_setprio(0);
      __builtin_amdgcn_s_barrier();
      // ---- phase B: m4-7, B reused in regs ----
#pragma unroll
      for (int m = 0; m < 4; ++m) {
        const int r = wr * 128 + (m + 4) * 16 + lr;
        afr[m] = *(const s16x8*)(cA + (size_t)r * 64 + (size_t)(((ks << 2) + g) ^ (r & 7)) * 8);
      }
      __builtin_amdgcn_s_setprio(1);
#pragma unroll
      for (int m = 0; m < 4; ++m)
#pragma unroll
        for (int n = 0; n < 4; ++n)
          acc[m + 4][n] = mfma16(afr[m], bfr[n], acc[m + 4][n]);
      __builtin_amdgcn_s_setprio(0);
      if (ks == 0) __builtin_amdgcn_s_barrier();
    }
    // boundary: t+1's stages (issued ~4 phases ago) must have landed
    asm volatile("s_waitcnt vmcnt(0)" ::: "memory");
    __builtin_amdgcn_s_barrier();
  }

  // epilogue
#pragma unroll
  for (int m = 0; m < 8; ++m)
#pragma unroll
    for (int n = 0; n < 4; ++n) {
      const int col = n0 + wn * 64 + n * 16 + lr;
      const float bv = bias[col];
      const int rrow0 = m0 + wr * 128 + m * 16 + g * 4;
      if (EPI == 3 && col >= 2048) {
        // V part -> transposed global layout [b][h][d][S], s contiguous
        const int col2 = col - 2048;
        bf16x4 pk;
#pragma unroll
        for (int i = 0; i < 4; ++i) pk[i] = (bf16_t)(acc[m][n][i] + bv);
        const size_t didx =
            ((((size_t)(rrow0 >> 11)) * 16 + (col2 >> 6)) * 64 + (col2 & 63)) * 2048 +
            (rrow0 & 2047);
        *(bf16x4*)&((bf16_t*)out2)[didx] = pk;
      } else {
#pragma unroll
        for (int i = 0; i < 4; ++i) {
          const int rrow = rrow0 + i;
          float v = acc[m][n][i] + bv;
          if (EPI == 1) {
            const size_t idx = (size_t)rrow * N + col;
            v += resid[idx];
            ((float*)out)[idx] = v;
          } else if (EPI == 2) {
            v = 0.5f * v * (1.0f + erff(v * 0.70710678118f));
            ((bf16_t*)out)[(size_t)rrow * N + col] = (bf16_t)v;
          } else if (EPI == 3) {
            ((bf16_t*)out)[(size_t)rrow * 2048 + col] = (bf16_t)v;
          } else {
            ((bf16_t*)out)[(size_t)rrow * N + col] = (bf16_t)v;
          }
        }
      }
    }
}

// ---------------- flash attention (swapped QK^T, staged K & V^T) ----------------
// qk:  bf16 [8192][2048]  (q at col 0, k at col 1024; head h at h*64)
// vt:  bf16 [64 bh][64 d][2048 s]
// O:   bf16 [8192][1024]
__global__ __launch_bounds__(256) void flash_attn2(const bf16_t* __restrict__ qk,
                                                   const bf16_t* __restrict__ vt,
                                                   bf16_t* __restrict__ O) {
  const int S = 2048;
  const int qt = blockIdx.x;   // 32 q-tiles of 64 rows
  const int bh = blockIdx.y;   // 64 (b,h)
  const int h = bh & 15;
  const size_t rowbase = (size_t)(bh >> 4) * S;
  const int tid = threadIdx.x, lane = tid & 63, wave = tid >> 6;
  const int g = lane >> 4, lr = lane & 15;
  const int q0w = qt * 64 + wave * 16;

  __shared__ __align__(16) bf16_t sK[64 * 64];    // [kv][d], XOR-swizzled chunks
  __shared__ __align__(16) bf16_t sVT[64 * 64];   // [d][kv], XOR-swizzled chunks
  __shared__ __align__(16) bf16_t sP[4][16 * 72]; // per-wave P[q][kv], pad 72

  const bf16_t* vtb = vt + (size_t)bh * 64 * 2048;

  // Q fragments: lane (g,lr) holds Q[q=lr][k=8g+j (+32*st)]
  s16x8 aq[2];
  {
    const bf16_t* qrow = qk + (rowbase + q0w + lr) * 2048 + h * 64;
    aq[0] = *(const s16x8*)(qrow + g * 8);
    aq[1] = *(const s16x8*)(qrow + 32 + g * 8);
  }

  f32x4 oa[4] = {};               // O^T[d = f2*16+4g+i][q = lr]
  float mrun = -1e30f, lrun = 0.0f;

  for (int kv0 = 0; kv0 < S; kv0 += 64) {
    __syncthreads();
    // stage K [64 kv][64 d] and VT [64 d][64 kv]; swizzled source, linear dest
#pragma unroll
    for (int p = 0; p < 2; ++p) {
      const int c = p * 256 + wave * 64 + lane;  // 16B chunk, 8 per row
      const int r = c >> 3;
      const int pb = (c & 7) ^ (r & 7);
      char* dK = (char*)sK + (size_t)(p * 256 + wave * 64) * 16;
      char* dV = (char*)sVT + (size_t)(p * 256 + wave * 64) * 16;
      gload_lds16(qk + (rowbase + kv0 + r) * 2048 + 1024 + h * 64 + pb * 8, dK);
      gload_lds16(vtb + (size_t)r * 2048 + kv0 + pb * 8, dV);
    }
    __syncthreads();

    // swapped QK^T: S^T[kv][q] = mfma(K, Q); lane holds S[q=lr][kv=fr*16+4g+i]
    f32x4 sc[4] = {};
#pragma unroll
    for (int st = 0; st < 2; ++st)
#pragma unroll
      for (int fr = 0; fr < 4; ++fr) {
        const int pb = (g + 4 * st) ^ (lr & 7);
        const s16x8 ak = *(const s16x8*)&sK[(fr * 16 + lr) * 64 + pb * 8];
        sc[fr] = mfma16(ak, aq[st], sc[fr]);
      }

    // online softmax: one q-row per lane, reduce across the 4 g-groups
    float rmax = -1e30f;
#pragma unroll
    for (int fr = 0; fr < 4; ++fr)
#pragma unroll
      for (int i = 0; i < 4; ++i) rmax = fmaxf(rmax, sc[fr][i]);
    rmax = fmaxf(rmax, __shfl_xor(rmax, 16));
    rmax = fmaxf(rmax, __shfl_xor(rmax, 32));
    const float mnew = fmaxf(mrun, rmax * 0.125f);
    const float alpha = __expf(mrun - mnew);
    mrun = mnew;
    float rsum = 0.0f;
#pragma unroll
    for (int fr = 0; fr < 4; ++fr)
#pragma unroll
      for (int i = 0; i < 4; ++i) {
        const float pp = __expf(sc[fr][i] * 0.125f - mnew);
        sc[fr][i] = pp;
        rsum += pp;
      }
    rsum += __shfl_xor(rsum, 16);
    rsum += __shfl_xor(rsum, 32);
    lrun = lrun * alpha + rsum;
#pragma unroll
    for (int f2 = 0; f2 < 4; ++f2)
#pragma unroll
      for (int i = 0; i < 4; ++i) oa[f2][i] *= alpha;

    // P[q=lr][kv]: in-lane kv-contiguous -> vectorized b64 writes (per-wave LDS)
#pragma unroll
    for (int fr = 0; fr < 4; ++fr) {
      bf16x4 pk;
#pragma unroll
      for (int i = 0; i < 4; ++i) pk[i] = (bf16_t)sc[fr][i];
      *(bf16x4*)&sP[wave][lr * 72 + fr * 16 + 4 * g] = pk;
    }

    // PV: O^T = mfma(VT-frag, P-frag)
#pragma unroll
    for (int st = 0; st < 2; ++st) {
      const s16x8 pa = *(const s16x8*)&sP[wave][lr * 72 + st * 32 + g * 8];
#pragma unroll
      for (int f2 = 0; f2 < 4; ++f2) {
        const int pb = (g + 4 * st) ^ (lr & 7);
        const s16x8 va = *(const s16x8*)&sVT[(f2 * 16 + lr) * 64 + pb * 8];
        oa[f2] = mfma16(va, pa, oa[f2]);
      }
    }
  }

  const float rl = 1.0f / lrun;
#pragma unroll
  for (int f2 = 0; f2 < 4; ++f2) {
    bf16x4 ov;
#pragma unroll
    for (int i = 0; i < 4; ++i) ov[i] = (bf16_t)(oa[f2][i] * rl);
    *(bf16x4*)&O[(rowbase + q0w + lr) * 1024 + h * 64 + f2 * 16 + 4 * g] = ov;
  }
}

// ---------------- launch ----------------
extern "C" void kernel_launch(void* const* d_in, const int* in_sizes, int n_in,
                              void* d_out, int out_size, void* d_ws, size_t ws_size,
                              hipStream_t stream) {
  const float* x    = (const float*)d_in[0];
  const float* ln1w = (const float*)d_in[1];
  const float* ln1b = (const float*)d_in[2];
  const float* Wqkv = (const float*)d_in[3];
  const float* bqkv = (const float*)d_in[4];
  const float* Wo   = (const float*)d_in[5];
  const float* bo   = (const float*)d_in[6];
  const float* ln2w = (const float*)d_in[7];
  const float* ln2b = (const float*)d_in[8];
  const float* fc1w = (const float*)d_in[9];
  const float* fc1b = (const float*)d_in[10];
  const float* fc2w = (const float*)d_in[11];
  const float* fc2b = (const float*)d_in[12];

  const int M = 8192;

  char* ws = (char*)d_ws;
  size_t off = 0;
  auto alloc = [&](size_t bytes) {
    char* p = ws + off;
    off += (bytes + 255) & ~(size_t)255;
    return p;
  };
  // persistent weights (bf16, transposed)
  bf16_t* WqkvT = (bf16_t*)alloc((size_t)3072 * 1024 * 2);   // 6 MB
  bf16_t* WoT   = (bf16_t*)alloc((size_t)1024 * 1024 * 2);   // 2 MB
  bf16_t* fc1T  = (bf16_t*)alloc((size_t)4096 * 1024 * 2);   // 8 MB
  bf16_t* fc2T  = (bf16_t*)alloc((size_t)1024 * 4096 * 2);   // 8 MB
  // activations
  bf16_t* h1    = (bf16_t*)alloc((size_t)M * 1024 * 2);      // 16 MB (reused as h2)
  bf16_t* qkQK  = (bf16_t*)alloc((size_t)M * 2048 * 2);      // 32 MB (attn region pt 1)
  bf16_t* vTg   = (bf16_t*)alloc((size_t)M * 1024 * 2);      // 16 MB (pt 2)
  bf16_t* attnO = (bf16_t*)alloc((size_t)M * 1024 * 2);      // 16 MB (pt 3)
  float*  x2    = (float*)alloc((size_t)M * 1024 * 4);       // 32 MB
  // aliases: lifetimes disjoint in stream order
  bf16_t* h2   = h1;     // h1 dead after QKV GEMM
  bf16_t* gbuf = qkQK;   // qkQK/vTg dead after attn, attnO dead after o-proj
  if (off > ws_size) return;  // ~136 MB required

  const dim3 tb(32, 8);
  tcast_kernel<<<dim3(96, 32), tb, 0, stream>>>(Wqkv, WqkvT, 1024, 3072);
  tcast_kernel<<<dim3(32, 32), tb, 0, stream>>>(Wo, WoT, 1024, 1024);
  tcast_kernel<<<dim3(128, 32), tb, 0, stream>>>(fc1w, fc1T, 1024, 4096);
  tcast_kernel<<<dim3(32, 128), tb, 0, stream>>>(fc2w, fc2T, 4096, 1024);

  ln_kernel<<<M, 256, 0, stream>>>(x, ln1w, ln1b, h1);

  gemm256<3><<<dim3(384), 512, 0, stream>>>(h1, WqkvT, bqkv, nullptr, qkQK, vTg, M, 3072, 1024);

  flash_attn2<<<dim3(32, 64), 256, 0, stream>>>(qkQK, vTg, attnO);

  gemm256<1><<<dim3(128), 512, 0, stream>>>(attnO, WoT, bo, x, x2, nullptr, M, 1024, 1024);

  ln_kernel<<<M, 256, 0, stream>>>(x2, ln2w, ln2b, h2);

  gemm256<2><<<dim3(512), 512, 0, stream>>>(h2, fc1T, fc1b, nullptr, gbuf, nullptr, M, 4096, 1024);

  gemm256<1><<<dim3(128), 512, 0, stream>>>(gbuf, fc2T, fc2b, x2, (float*)d_out, nullptr, M, 1024, 4096);
}

// Round 6
// 510.736 us; speedup vs baseline: 1.0911x; 1.0911x over previous
//
#include <hip/hip_runtime.h>
#include <hip/hip_bf16.h>
#include <math.h>

typedef __bf16 bf16_t;
typedef __bf16 bf16x4 __attribute__((ext_vector_type(4)));
typedef short  s16x8  __attribute__((ext_vector_type(8)));
typedef float  f32x4  __attribute__((ext_vector_type(4)));

#define DEVINL __device__ __forceinline__

DEVINL void gload_lds16(const void* g, void* l) {
  __builtin_amdgcn_global_load_lds(
      (const __attribute__((address_space(1))) unsigned int*)g,
      (__attribute__((address_space(3))) unsigned int*)l, 16, 0, 0);
}

DEVINL f32x4 mfma16(s16x8 a, s16x8 b, f32x4 c) {
  return __builtin_amdgcn_mfma_f32_16x16x32_bf16(a, b, c, 0, 0, 0);
}

template <int N> DEVINL void waitv() {
  if constexpr (N == 0) asm volatile("s_waitcnt vmcnt(0)" ::: "memory");
  else if constexpr (N == 3) asm volatile("s_waitcnt vmcnt(3)" ::: "memory");
  else if constexpr (N == 4) asm volatile("s_waitcnt vmcnt(4)" ::: "memory");
  else if constexpr (N == 6) asm volatile("s_waitcnt vmcnt(6)" ::: "memory");
  else if constexpr (N == 8) asm volatile("s_waitcnt vmcnt(8)" ::: "memory");
}

// ---------------- transpose + cast: W[K][N] f32 -> WT[N][K] bf16 ----------------
__global__ __launch_bounds__(256) void tcast_kernel(const float* __restrict__ W,
                                                    bf16_t* __restrict__ WT,
                                                    int K, int N) {
  __shared__ float tile[32][33];
  const int n0 = blockIdx.x * 32, k0 = blockIdx.y * 32;
  const int tx = threadIdx.x, ty = threadIdx.y;
#pragma unroll
  for (int j = 0; j < 4; ++j)
    tile[ty + j * 8][tx] = W[(size_t)(k0 + ty + j * 8) * N + (n0 + tx)];
  __syncthreads();
#pragma unroll
  for (int j = 0; j < 4; ++j)
    WT[(size_t)(n0 + ty + j * 8) * K + (k0 + tx)] = (bf16_t)tile[tx][ty + j * 8];
}

// ---------------- layernorm: f32 [rows][1024] -> bf16 ----------------
__global__ __launch_bounds__(256) void ln_kernel(const float* __restrict__ x,
                                                 const float* __restrict__ w,
                                                 const float* __restrict__ b,
                                                 bf16_t* __restrict__ out) {
  const int row = blockIdx.x, tid = threadIdx.x;
  const float4 v = ((const float4*)(x + (size_t)row * 1024))[tid];
  float s  = v.x + v.y + v.z + v.w;
  float s2 = v.x * v.x + v.y * v.y + v.z * v.z + v.w * v.w;
#pragma unroll
  for (int off = 32; off > 0; off >>= 1) {
    s  += __shfl_down(s, off);
    s2 += __shfl_down(s2, off);
  }
  __shared__ float red[8];
  const int wave = tid >> 6, lane = tid & 63;
  if (lane == 0) { red[wave] = s; red[4 + wave] = s2; }
  __syncthreads();
  s  = red[0] + red[1] + red[2] + red[3];
  s2 = red[4] + red[5] + red[6] + red[7];
  const float mu = s * (1.0f / 1024.0f);
  const float rs = rsqrtf(s2 * (1.0f / 1024.0f) - mu * mu + 1e-5f);
  const float4 wv = ((const float4*)w)[tid];
  const float4 bv = ((const float4*)b)[tid];
  bf16x4 o;
  o[0] = (bf16_t)((v.x - mu) * rs * wv.x + bv.x);
  o[1] = (bf16_t)((v.y - mu) * rs * wv.y + bv.y);
  o[2] = (bf16_t)((v.z - mu) * rs * wv.z + bv.z);
  o[3] = (bf16_t)((v.w - mu) * rs * wv.w + bv.w);
  ((bf16x4*)(out + (size_t)row * 1024))[tid] = o;
}

// ---------------- pipelined 256xBN GEMM, counted-vmcnt half-slot ring ----------
// C[M][N] = A[M][K] (bf16) * BT[N][K]^T + epi. 8 waves (2M x 4N), per-wave
// 128 x (NF*16). Half-slot = A[256][32]+B[BN][32] (K=32), ring of 4 slots;
// while computing slot n we stage slot n+3 (3 in flight). End-of-slot wait is
// vmcnt(2*LPS) -- never 0 in the main loop (T4). T2 chunk-XOR swizzle, T5
// setprio around MFMA clusters.
// EPI 0: +bias -> bf16 | 1: +bias+resid -> f32 | 2: gelu -> bf16 | 3: qkv split
template <int EPI, int NF>
__global__ __launch_bounds__(512, 1) void gemmP(const bf16_t* __restrict__ A,
                                                const bf16_t* __restrict__ BT,
                                                const float* __restrict__ bias,
                                                const float* __restrict__ resid,
                                                void* __restrict__ out,
                                                void* __restrict__ out2,
                                                int M, int N, int K) {
  constexpr int BN = NF * 64;          // 256 or 128
  constexpr int BQ = BN >> 7;          // B load-groups per slot: 2 or 1
  constexpr int LPS = 2 + BQ;          // loads/thread per slot: 4 or 3
  constexpr int SLOT = 8192 + BN * 32; // elems per slot
  __shared__ __align__(16) bf16_t sh[4 * SLOT];

  const int tid = threadIdx.x;
  const int lane = tid & 63, wave = tid >> 6;
  const int wr = wave >> 2, wn = wave & 3;
  const int g = lane >> 4, lr = lane & 15;

  // bijective XCD swizzle (all grids are multiples of 8); M/256 == 32
  const int nwg = gridDim.x, bid = blockIdx.x;
  const int swz = (bid & 7) * (nwg >> 3) + (bid >> 3);
  const int m0 = (swz & 31) * 256, n0 = (swz >> 5) * BN;
  const bf16_t* Ag = A + (size_t)m0 * K;
  const bf16_t* Bg = BT + (size_t)n0 * K;

  f32x4 acc[8][NF] = {};
  const int H = K >> 5;  // half-slots (K=1024 -> 32, K=4096 -> 128)

  auto stageA = [&](int n) {
    const int kb = n << 5;
    bf16_t* dst = sh + (size_t)(n & 3) * SLOT;
#pragma unroll
    for (int q = 0; q < 2; ++q) {
      const int c = q * 512 + tid;
      const int r = c >> 2;
      const int j = (c & 3) ^ (r & 3);
      gload_lds16(Ag + (size_t)r * K + kb + j * 8,
                  dst + (size_t)(q * 512 + wave * 64) * 8);
    }
  };
  auto stageB = [&](int n) {
    const int kb = n << 5;
    bf16_t* dst = sh + (size_t)(n & 3) * SLOT + 8192;
#pragma unroll
    for (int q = 0; q < BQ; ++q) {
      const int c = q * 512 + tid;
      const int r = c >> 2;
      const int j = (c & 3) ^ (r & 3);
      gload_lds16(Bg + (size_t)r * K + kb + j * 8,
                  dst + (size_t)(q * 512 + wave * 64) * 8);
    }
  };

  // prologue: stage slots 0,1,2 (H >= 32 always)
  stageA(0); stageB(0);
  stageA(1); stageB(1);
  stageA(2); stageB(2);
  waitv<2 * LPS>();
  __builtin_amdgcn_s_barrier();

  for (int n = 0; n < H; ++n) {
    const bf16_t* sa = sh + (size_t)(n & 3) * SLOT;
    const bf16_t* sb = sa + 8192;
    const bool doStage = (n + 3 < H);
    s16x8 afr[4], bfr[NF];
    // ---- phase A: B-frags + A m0-3, stage A of slot n+3 ----
#pragma unroll
    for (int nn = 0; nn < NF; ++nn) {
      const int r = wn * (NF * 16) + nn * 16 + lr;
      bfr[nn] = *(const s16x8*)(sb + (size_t)r * 32 + (size_t)(g ^ (r & 3)) * 8);
    }
#pragma unroll
    for (int m = 0; m < 4; ++m) {
      const int r = wr * 128 + m * 16 + lr;
      afr[m] = *(const s16x8*)(sa + (size_t)r * 32 + (size_t)(g ^ (r & 3)) * 8);
    }
    if (doStage) stageA(n + 3);
    __builtin_amdgcn_s_setprio(1);
#pragma unroll
    for (int m = 0; m < 4; ++m)
#pragma unroll
      for (int nn = 0; nn < NF; ++nn)
        acc[m][nn] = mfma16(afr[m], bfr[nn], acc[m][nn]);
    __builtin_amdgcn_s_setprio(0);
    __builtin_amdgcn_s_barrier();
    // ---- phase B: A m4-7 (B reused), stage B of slot n+3 ----
#pragma unroll
    for (int m = 0; m < 4; ++m) {
      const int r = wr * 128 + (m + 4) * 16 + lr;
      afr[m] = *(const s16x8*)(sa + (size_t)r * 32 + (size_t)(g ^ (r & 3)) * 8);
    }
    if (doStage) stageB(n + 3);
    __builtin_amdgcn_s_setprio(1);
#pragma unroll
    for (int m = 0; m < 4; ++m)
#pragma unroll
      for (int nn = 0; nn < NF; ++nn)
        acc[m + 4][nn] = mfma16(afr[m], bfr[nn], acc[m + 4][nn]);
    __builtin_amdgcn_s_setprio(0);
    // ---- end of slot: counted wait (slot n+1 landed; n+2,n+3 in flight) ----
    if (n + 3 < H)            waitv<2 * LPS>();
    else if (n + 2 == H - 1)  waitv<LPS>();
    else                      waitv<0>();
    __builtin_amdgcn_s_barrier();
  }

  // epilogue
#pragma unroll
  for (int m = 0; m < 8; ++m)
#pragma unroll
    for (int nn = 0; nn < NF; ++nn) {
      const int col = n0 + wn * (NF * 16) + nn * 16 + lr;
      const float bv = bias[col];
      const int rrow0 = m0 + wr * 128 + m * 16 + g * 4;
      if (EPI == 3 && col >= 2048) {
        const int col2 = col - 2048;
        bf16x4 pk;
#pragma unroll
        for (int i = 0; i < 4; ++i) pk[i] = (bf16_t)(acc[m][nn][i] + bv);
        const size_t didx =
            ((((size_t)(rrow0 >> 11)) * 16 + (col2 >> 6)) * 64 + (col2 & 63)) * 2048 +
            (rrow0 & 2047);
        *(bf16x4*)&((bf16_t*)out2)[didx] = pk;
      } else {
#pragma unroll
        for (int i = 0; i < 4; ++i) {
          const int rrow = rrow0 + i;
          float v = acc[m][nn][i] + bv;
          if (EPI == 1) {
            const size_t idx = (size_t)rrow * N + col;
            v += resid[idx];
            ((float*)out)[idx] = v;
          } else if (EPI == 2) {
            v = 0.5f * v * (1.0f + erff(v * 0.70710678118f));
            ((bf16_t*)out)[(size_t)rrow * N + col] = (bf16_t)v;
          } else if (EPI == 3) {
            ((bf16_t*)out)[(size_t)rrow * 2048 + col] = (bf16_t)v;
          } else {
            ((bf16_t*)out)[(size_t)rrow * N + col] = (bf16_t)v;
          }
        }
      }
    }
}

// ---------------- flash attention (swapped QK^T, staged K & V^T) ----------------
// qk:  bf16 [8192][2048]  (q at col 0, k at col 1024; head h at h*64)
// vt:  bf16 [64 bh][64 d][2048 s]
// O:   bf16 [8192][1024]
__global__ __launch_bounds__(256) void flash_attn2(const bf16_t* __restrict__ qk,
                                                   const bf16_t* __restrict__ vt,
                                                   bf16_t* __restrict__ O) {
  const int S = 2048;
  const int qt = blockIdx.x;
  const int bh = blockIdx.y;
  const int h = bh & 15;
  const size_t rowbase = (size_t)(bh >> 4) * S;
  const int tid = threadIdx.x, lane = tid & 63, wave = tid >> 6;
  const int g = lane >> 4, lr = lane & 15;
  const int q0w = qt * 64 + wave * 16;

  __shared__ __align__(16) bf16_t sK[64 * 64];
  __shared__ __align__(16) bf16_t sVT[64 * 64];
  __shared__ __align__(16) bf16_t sP[4][16 * 72];

  const bf16_t* vtb = vt + (size_t)bh * 64 * 2048;

  s16x8 aq[2];
  {
    const bf16_t* qrow = qk + (rowbase + q0w + lr) * 2048 + h * 64;
    aq[0] = *(const s16x8*)(qrow + g * 8);
    aq[1] = *(const s16x8*)(qrow + 32 + g * 8);
  }

  f32x4 oa[4] = {};
  float mrun = -1e30f, lrun = 0.0f;

  for (int kv0 = 0; kv0 < S; kv0 += 64) {
    __syncthreads();
#pragma unroll
    for (int p = 0; p < 2; ++p) {
      const int c = p * 256 + wave * 64 + lane;
      const int r = c >> 3;
      const int pb = (c & 7) ^ (r & 7);
      char* dK = (char*)sK + (size_t)(p * 256 + wave * 64) * 16;
      char* dV = (char*)sVT + (size_t)(p * 256 + wave * 64) * 16;
      gload_lds16(qk + (rowbase + kv0 + r) * 2048 + 1024 + h * 64 + pb * 8, dK);
      gload_lds16(vtb + (size_t)r * 2048 + kv0 + pb * 8, dV);
    }
    __syncthreads();

    f32x4 sc[4] = {};
#pragma unroll
    for (int st = 0; st < 2; ++st)
#pragma unroll
      for (int fr = 0; fr < 4; ++fr) {
        const int pb = (g + 4 * st) ^ (lr & 7);
        const s16x8 ak = *(const s16x8*)&sK[(fr * 16 + lr) * 64 + pb * 8];
        sc[fr] = mfma16(ak, aq[st], sc[fr]);
      }

    float rmax = -1e30f;
#pragma unroll
    for (int fr = 0; fr < 4; ++fr)
#pragma unroll
      for (int i = 0; i < 4; ++i) rmax = fmaxf(rmax, sc[fr][i]);
    rmax = fmaxf(rmax, __shfl_xor(rmax, 16));
    rmax = fmaxf(rmax, __shfl_xor(rmax, 32));
    const float mnew = fmaxf(mrun, rmax * 0.125f);
    const float alpha = __expf(mrun - mnew);
    mrun = mnew;
    float rsum = 0.0f;
#pragma unroll
    for (int fr = 0; fr < 4; ++fr)
#pragma unroll
      for (int i = 0; i < 4; ++i) {
        const float pp = __expf(sc[fr][i] * 0.125f - mnew);
        sc[fr][i] = pp;
        rsum += pp;
      }
    rsum += __shfl_xor(rsum, 16);
    rsum += __shfl_xor(rsum, 32);
    lrun = lrun * alpha + rsum;
#pragma unroll
    for (int f2 = 0; f2 < 4; ++f2)
#pragma unroll
      for (int i = 0; i < 4; ++i) oa[f2][i] *= alpha;

#pragma unroll
    for (int fr = 0; fr < 4; ++fr) {
      bf16x4 pk;
#pragma unroll
      for (int i = 0; i < 4; ++i) pk[i] = (bf16_t)sc[fr][i];
      *(bf16x4*)&sP[wave][lr * 72 + fr * 16 + 4 * g] = pk;
    }

#pragma unroll
    for (int st = 0; st < 2; ++st) {
      const s16x8 pa = *(const s16x8*)&sP[wave][lr * 72 + st * 32 + g * 8];
#pragma unroll
      for (int f2 = 0; f2 < 4; ++f2) {
        const int pb = (g + 4 * st) ^ (lr & 7);
        const s16x8 va = *(const s16x8*)&sVT[(f2 * 16 + lr) * 64 + pb * 8];
        oa[f2] = mfma16(va, pa, oa[f2]);
      }
    }
  }

  const float rl = 1.0f / lrun;
#pragma unroll
  for (int f2 = 0; f2 < 4; ++f2) {
    bf16x4 ov;
#pragma unroll
    for (int i = 0; i < 4; ++i) ov[i] = (bf16_t)(oa[f2][i] * rl);
    *(bf16x4*)&O[(rowbase + q0w + lr) * 1024 + h * 64 + f2 * 16 + 4 * g] = ov;
  }
}

// ---------------- launch ----------------
extern "C" void kernel_launch(void* const* d_in, const int* in_sizes, int n_in,
                              void* d_out, int out_size, void* d_ws, size_t ws_size,
                              hipStream_t stream) {
  const float* x    = (const float*)d_in[0];
  const float* ln1w = (const float*)d_in[1];
  const float* ln1b = (const float*)d_in[2];
  const float* Wqkv = (const float*)d_in[3];
  const float* bqkv = (const float*)d_in[4];
  const float* Wo   = (const float*)d_in[5];
  const float* bo   = (const float*)d_in[6];
  const float* ln2w = (const float*)d_in[7];
  const float* ln2b = (const float*)d_in[8];
  const float* fc1w = (const float*)d_in[9];
  const float* fc1b = (const float*)d_in[10];
  const float* fc2w = (const float*)d_in[11];
  const float* fc2b = (const float*)d_in[12];

  const int M = 8192;

  char* ws = (char*)d_ws;
  size_t off = 0;
  auto alloc = [&](size_t bytes) {
    char* p = ws + off;
    off += (bytes + 255) & ~(size_t)255;
    return p;
  };
  // persistent weights (bf16, transposed)
  bf16_t* WqkvT = (bf16_t*)alloc((size_t)3072 * 1024 * 2);   // 6 MB
  bf16_t* WoT   = (bf16_t*)alloc((size_t)1024 * 1024 * 2);   // 2 MB
  bf16_t* fc1T  = (bf16_t*)alloc((size_t)4096 * 1024 * 2);   // 8 MB
  bf16_t* fc2T  = (bf16_t*)alloc((size_t)1024 * 4096 * 2);   // 8 MB
  // activations
  bf16_t* h1    = (bf16_t*)alloc((size_t)M * 1024 * 2);      // 16 MB (reused as h2)
  bf16_t* qkQK  = (bf16_t*)alloc((size_t)M * 2048 * 2);      // 32 MB (attn region pt 1)
  bf16_t* vTg   = (bf16_t*)alloc((size_t)M * 1024 * 2);      // 16 MB (pt 2)
  bf16_t* attnO = (bf16_t*)alloc((size_t)M * 1024 * 2);      // 16 MB (pt 3)
  float*  x2    = (float*)alloc((size_t)M * 1024 * 4);       // 32 MB
  // aliases: lifetimes disjoint in stream order
  bf16_t* h2   = h1;     // h1 dead after QKV GEMM
  bf16_t* gbuf = qkQK;   // qkQK/vTg dead after attn, attnO dead after o-proj
  if (off > ws_size) return;  // ~136 MB required

  const dim3 tb(32, 8);
  tcast_kernel<<<dim3(96, 32), tb, 0, stream>>>(Wqkv, WqkvT, 1024, 3072);
  tcast_kernel<<<dim3(32, 32), tb, 0, stream>>>(Wo, WoT, 1024, 1024);
  tcast_kernel<<<dim3(128, 32), tb, 0, stream>>>(fc1w, fc1T, 1024, 4096);
  tcast_kernel<<<dim3(32, 128), tb, 0, stream>>>(fc2w, fc2T, 4096, 1024);

  ln_kernel<<<M, 256, 0, stream>>>(x, ln1w, ln1b, h1);

  gemmP<3, 4><<<dim3(384), 512, 0, stream>>>(h1, WqkvT, bqkv, nullptr, qkQK, vTg, M, 3072, 1024);

  flash_attn2<<<dim3(32, 64), 256, 0, stream>>>(qkQK, vTg, attnO);

  gemmP<1, 2><<<dim3(256), 512, 0, stream>>>(attnO, WoT, bo, x, x2, nullptr, M, 1024, 1024);

  ln_kernel<<<M, 256, 0, stream>>>(x2, ln2w, ln2b, h2);

  gemmP<2, 4><<<dim3(512), 512, 0, stream>>>(h2, fc1T, fc1b, nullptr, gbuf, nullptr, M, 4096, 1024);

  gemmP<1, 2><<<dim3(256), 512, 0, stream>>>(gbuf, fc2T, fc2b, x2, (float*)d_out, nullptr, M, 1024, 4096);
}

// Round 7
// 449.033 us; speedup vs baseline: 1.2410x; 1.1374x over previous
//
#include <hip/hip_runtime.h>
#include <hip/hip_bf16.h>
#include <math.h>

typedef __bf16 bf16_t;
typedef __bf16 bf16x4 __attribute__((ext_vector_type(4)));
typedef short  s16x8  __attribute__((ext_vector_type(8)));
typedef float  f32x4  __attribute__((ext_vector_type(4)));

#define DEVINL __device__ __forceinline__

DEVINL void gload_lds16(const void* g, void* l) {
  __builtin_amdgcn_global_load_lds(
      (const __attribute__((address_space(1))) unsigned int*)g,
      (__attribute__((address_space(3))) unsigned int*)l, 16, 0, 0);
}

DEVINL f32x4 mfma16(s16x8 a, s16x8 b, f32x4 c) {
  return __builtin_amdgcn_mfma_f32_16x16x32_bf16(a, b, c, 0, 0, 0);
}

// ---------------- transpose + cast: W[K][N] f32 -> WT[N][K] bf16 ----------------
__global__ __launch_bounds__(256) void tcast_kernel(const float* __restrict__ W,
                                                    bf16_t* __restrict__ WT,
                                                    int K, int N) {
  __shared__ float tile[32][33];
  const int n0 = blockIdx.x * 32, k0 = blockIdx.y * 32;
  const int tx = threadIdx.x, ty = threadIdx.y;
#pragma unroll
  for (int j = 0; j < 4; ++j)
    tile[ty + j * 8][tx] = W[(size_t)(k0 + ty + j * 8) * N + (n0 + tx)];
  __syncthreads();
#pragma unroll
  for (int j = 0; j < 4; ++j)
    WT[(size_t)(n0 + ty + j * 8) * K + (k0 + tx)] = (bf16_t)tile[tx][ty + j * 8];
}

// ---------------- layernorm: f32 [rows][1024] -> bf16 ----------------
__global__ __launch_bounds__(256) void ln_kernel(const float* __restrict__ x,
                                                 const float* __restrict__ w,
                                                 const float* __restrict__ b,
                                                 bf16_t* __restrict__ out) {
  const int row = blockIdx.x, tid = threadIdx.x;
  const float4 v = ((const float4*)(x + (size_t)row * 1024))[tid];
  float s  = v.x + v.y + v.z + v.w;
  float s2 = v.x * v.x + v.y * v.y + v.z * v.z + v.w * v.w;
#pragma unroll
  for (int off = 32; off > 0; off >>= 1) {
    s  += __shfl_down(s, off);
    s2 += __shfl_down(s2, off);
  }
  __shared__ float red[8];
  const int wave = tid >> 6, lane = tid & 63;
  if (lane == 0) { red[wave] = s; red[4 + wave] = s2; }
  __syncthreads();
  s  = red[0] + red[1] + red[2] + red[3];
  s2 = red[4] + red[5] + red[6] + red[7];
  const float mu = s * (1.0f / 1024.0f);
  const float rs = rsqrtf(s2 * (1.0f / 1024.0f) - mu * mu + 1e-5f);
  const float4 wv = ((const float4*)w)[tid];
  const float4 bv = ((const float4*)b)[tid];
  bf16x4 o;
  o[0] = (bf16_t)((v.x - mu) * rs * wv.x + bv.x);
  o[1] = (bf16_t)((v.y - mu) * rs * wv.y + bv.y);
  o[2] = (bf16_t)((v.z - mu) * rs * wv.z + bv.z);
  o[3] = (bf16_t)((v.w - mu) * rs * wv.w + bv.w);
  ((bf16x4*)(out + (size_t)row * 1024))[tid] = o;
}

// ---------------- 128x128 GEMM, BK=64, TLP-based (m97 family) ----------------
// C[M][N] = A[M][K] (bf16) * BT[N][K]^T + epi. 4 waves (2x2), acc 4x4.
// [128][64] tiles (128B rows): stage via gload_lds with inverse-swizzled
// source (chunk^(row&7)); frag reads swizzled the same way -> 2-way (free)
// bank access per quarter-wave. Single 32KB buffer; occupancy 4+ blocks/CU
// provides the overlap (m114). XCD-chunked 1D grid for B-panel L2 locality.
// EPI 0: +bias -> bf16 | 1: +bias+resid -> f32 | 2: gelu -> bf16 | 3: qkv split
template <int EPI>
__global__ __launch_bounds__(256, 4) void gemm128b(const bf16_t* __restrict__ A,
                                                   const bf16_t* __restrict__ BT,
                                                   const float* __restrict__ bias,
                                                   const float* __restrict__ resid,
                                                   void* __restrict__ out,
                                                   void* __restrict__ out2,
                                                   int M, int N, int K) {
  __shared__ __align__(16) bf16_t sA[128 * 64];
  __shared__ __align__(16) bf16_t sB[128 * 64];
  const int tid = threadIdx.x;
  const int lane = tid & 63, wave = tid >> 6;
  const int wr = wave >> 1, wc = wave & 1;
  const int g = lane >> 4, lr = lane & 15;

  // XCD-chunked swizzle: n-major chunks per XCD (all grids %8==0, M/128==64)
  const int bid = blockIdx.x;
  const int cpx = gridDim.x >> 3;
  const int gid = (bid & 7) * cpx + (bid >> 3);
  const int m0 = (gid & 63) * 128, n0 = (gid >> 6) * 128;
  const bf16_t* Ab = A + (size_t)m0 * K;
  const bf16_t* Bb = BT + (size_t)n0 * K;

  f32x4 acc[4][4] = {};

  for (int kt = 0; kt < K; kt += 64) {
    __syncthreads();
    // stage [128][64] A and B: 1024 chunks each, 4 per thread
#pragma unroll
    for (int q = 0; q < 4; ++q) {
      const int c = q * 256 + tid;
      const int r = c >> 3;
      const int j = (c & 7) ^ (r & 7);
      const size_t doff = (size_t)(q * 256 + wave * 64) * 8;
      gload_lds16(Ab + (size_t)r * K + kt + j * 8, sA + doff);
      gload_lds16(Bb + (size_t)r * K + kt + j * 8, sB + doff);
    }
    __syncthreads();
#pragma unroll
    for (int ks = 0; ks < 2; ++ks) {
      s16x8 af[4], bfr[4];
#pragma unroll
      for (int m = 0; m < 4; ++m) {
        const int r = wr * 64 + m * 16 + lr;
        af[m] = *(const s16x8*)&sA[r * 64 + (((ks << 2) + g) ^ (r & 7)) * 8];
      }
#pragma unroll
      for (int n = 0; n < 4; ++n) {
        const int r = wc * 64 + n * 16 + lr;
        bfr[n] = *(const s16x8*)&sB[r * 64 + (((ks << 2) + g) ^ (r & 7)) * 8];
      }
#pragma unroll
      for (int m = 0; m < 4; ++m)
#pragma unroll
        for (int n = 0; n < 4; ++n)
          acc[m][n] = mfma16(af[m], bfr[n], acc[m][n]);
    }
  }

#pragma unroll
  for (int m = 0; m < 4; ++m)
#pragma unroll
    for (int n = 0; n < 4; ++n) {
      const int col = n0 + wc * 64 + n * 16 + lr;
      const float bv = bias[col];
      const int rrow0 = m0 + wr * 64 + m * 16 + g * 4;
      if (EPI == 3 && col >= 2048) {
        // V part -> transposed global layout [b][h][d][S], s contiguous
        const int col2 = col - 2048;
        bf16x4 pk;
#pragma unroll
        for (int i = 0; i < 4; ++i) pk[i] = (bf16_t)(acc[m][n][i] + bv);
        const size_t didx =
            ((((size_t)(rrow0 >> 11)) * 16 + (col2 >> 6)) * 64 + (col2 & 63)) * 2048 +
            (rrow0 & 2047);
        *(bf16x4*)&((bf16_t*)out2)[didx] = pk;
      } else {
#pragma unroll
        for (int i = 0; i < 4; ++i) {
          const int rrow = rrow0 + i;
          float v = acc[m][n][i] + bv;
          if (EPI == 1) {
            const size_t idx = (size_t)rrow * N + col;
            v += resid[idx];
            ((float*)out)[idx] = v;
          } else if (EPI == 2) {
            v = 0.5f * v * (1.0f + erff(v * 0.70710678118f));
            ((bf16_t*)out)[(size_t)rrow * N + col] = (bf16_t)v;
          } else if (EPI == 3) {
            ((bf16_t*)out)[(size_t)rrow * 2048 + col] = (bf16_t)v;
          } else {
            ((bf16_t*)out)[(size_t)rrow * N + col] = (bf16_t)v;
          }
        }
      }
    }
}

// ---------------- flash attention (swapped QK^T, staged K & V^T) ----------------
// qk:  bf16 [8192][2048]  (q at col 0, k at col 1024; head h at h*64)
// vt:  bf16 [64 bh][64 d][2048 s]
// O:   bf16 [8192][1024]
__global__ __launch_bounds__(256) void flash_attn2(const bf16_t* __restrict__ qk,
                                                   const bf16_t* __restrict__ vt,
                                                   bf16_t* __restrict__ O) {
  const int S = 2048;
  const int qt = blockIdx.x;
  const int bh = blockIdx.y;
  const int h = bh & 15;
  const size_t rowbase = (size_t)(bh >> 4) * S;
  const int tid = threadIdx.x, lane = tid & 63, wave = tid >> 6;
  const int g = lane >> 4, lr = lane & 15;
  const int q0w = qt * 64 + wave * 16;

  __shared__ __align__(16) bf16_t sK[64 * 64];
  __shared__ __align__(16) bf16_t sVT[64 * 64];
  __shared__ __align__(16) bf16_t sP[4][16 * 72];

  const bf16_t* vtb = vt + (size_t)bh * 64 * 2048;

  s16x8 aq[2];
  {
    const bf16_t* qrow = qk + (rowbase + q0w + lr) * 2048 + h * 64;
    aq[0] = *(const s16x8*)(qrow + g * 8);
    aq[1] = *(const s16x8*)(qrow + 32 + g * 8);
  }

  f32x4 oa[4] = {};
  float mrun = -1e30f, lrun = 0.0f;

  for (int kv0 = 0; kv0 < S; kv0 += 64) {
    __syncthreads();
#pragma unroll
    for (int p = 0; p < 2; ++p) {
      const int c = p * 256 + wave * 64 + lane;
      const int r = c >> 3;
      const int pb = (c & 7) ^ (r & 7);
      char* dK = (char*)sK + (size_t)(p * 256 + wave * 64) * 16;
      char* dV = (char*)sVT + (size_t)(p * 256 + wave * 64) * 16;
      gload_lds16(qk + (rowbase + kv0 + r) * 2048 + 1024 + h * 64 + pb * 8, dK);
      gload_lds16(vtb + (size_t)r * 2048 + kv0 + pb * 8, dV);
    }
    __syncthreads();

    f32x4 sc[4] = {};
#pragma unroll
    for (int st = 0; st < 2; ++st)
#pragma unroll
      for (int fr = 0; fr < 4; ++fr) {
        const int pb = (g + 4 * st) ^ (lr & 7);
        const s16x8 ak = *(const s16x8*)&sK[(fr * 16 + lr) * 64 + pb * 8];
        sc[fr] = mfma16(ak, aq[st], sc[fr]);
      }

    float rmax = -1e30f;
#pragma unroll
    for (int fr = 0; fr < 4; ++fr)
#pragma unroll
      for (int i = 0; i < 4; ++i) rmax = fmaxf(rmax, sc[fr][i]);
    rmax = fmaxf(rmax, __shfl_xor(rmax, 16));
    rmax = fmaxf(rmax, __shfl_xor(rmax, 32));
    const float mnew = fmaxf(mrun, rmax * 0.125f);
    const float alpha = __expf(mrun - mnew);
    mrun = mnew;
    float rsum = 0.0f;
#pragma unroll
    for (int fr = 0; fr < 4; ++fr)
#pragma unroll
      for (int i = 0; i < 4; ++i) {
        const float pp = __expf(sc[fr][i] * 0.125f - mnew);
        sc[fr][i] = pp;
        rsum += pp;
      }
    rsum += __shfl_xor(rsum, 16);
    rsum += __shfl_xor(rsum, 32);
    lrun = lrun * alpha + rsum;
#pragma unroll
    for (int f2 = 0; f2 < 4; ++f2)
#pragma unroll
      for (int i = 0; i < 4; ++i) oa[f2][i] *= alpha;

#pragma unroll
    for (int fr = 0; fr < 4; ++fr) {
      bf16x4 pk;
#pragma unroll
      for (int i = 0; i < 4; ++i) pk[i] = (bf16_t)sc[fr][i];
      *(bf16x4*)&sP[wave][lr * 72 + fr * 16 + 4 * g] = pk;
    }

#pragma unroll
    for (int st = 0; st < 2; ++st) {
      const s16x8 pa = *(const s16x8*)&sP[wave][lr * 72 + st * 32 + g * 8];
#pragma unroll
      for (int f2 = 0; f2 < 4; ++f2) {
        const int pb = (g + 4 * st) ^ (lr & 7);
        const s16x8 va = *(const s16x8*)&sVT[(f2 * 16 + lr) * 64 + pb * 8];
        oa[f2] = mfma16(va, pa, oa[f2]);
      }
    }
  }

  const float rl = 1.0f / lrun;
#pragma unroll
  for (int f2 = 0; f2 < 4; ++f2) {
    bf16x4 ov;
#pragma unroll
    for (int i = 0; i < 4; ++i) ov[i] = (bf16_t)(oa[f2][i] * rl);
    *(bf16x4*)&O[(rowbase + q0w + lr) * 1024 + h * 64 + f2 * 16 + 4 * g] = ov;
  }
}

// ---------------- launch ----------------
extern "C" void kernel_launch(void* const* d_in, const int* in_sizes, int n_in,
                              void* d_out, int out_size, void* d_ws, size_t ws_size,
                              hipStream_t stream) {
  const float* x    = (const float*)d_in[0];
  const float* ln1w = (const float*)d_in[1];
  const float* ln1b = (const float*)d_in[2];
  const float* Wqkv = (const float*)d_in[3];
  const float* bqkv = (const float*)d_in[4];
  const float* Wo   = (const float*)d_in[5];
  const float* bo   = (const float*)d_in[6];
  const float* ln2w = (const float*)d_in[7];
  const float* ln2b = (const float*)d_in[8];
  const float* fc1w = (const float*)d_in[9];
  const float* fc1b = (const float*)d_in[10];
  const float* fc2w = (const float*)d_in[11];
  const float* fc2b = (const float*)d_in[12];

  const int M = 8192;

  char* ws = (char*)d_ws;
  size_t off = 0;
  auto alloc = [&](size_t bytes) {
    char* p = ws + off;
    off += (bytes + 255) & ~(size_t)255;
    return p;
  };
  // persistent weights (bf16, transposed)
  bf16_t* WqkvT = (bf16_t*)alloc((size_t)3072 * 1024 * 2);   // 6 MB
  bf16_t* WoT   = (bf16_t*)alloc((size_t)1024 * 1024 * 2);   // 2 MB
  bf16_t* fc1T  = (bf16_t*)alloc((size_t)4096 * 1024 * 2);   // 8 MB
  bf16_t* fc2T  = (bf16_t*)alloc((size_t)1024 * 4096 * 2);   // 8 MB
  // activations
  bf16_t* h1    = (bf16_t*)alloc((size_t)M * 1024 * 2);      // 16 MB (reused as h2)
  bf16_t* qkQK  = (bf16_t*)alloc((size_t)M * 2048 * 2);      // 32 MB (attn region pt 1)
  bf16_t* vTg   = (bf16_t*)alloc((size_t)M * 1024 * 2);      // 16 MB (pt 2)
  bf16_t* attnO = (bf16_t*)alloc((size_t)M * 1024 * 2);      // 16 MB (pt 3)
  float*  x2    = (float*)alloc((size_t)M * 1024 * 4);       // 32 MB
  // aliases: lifetimes disjoint in stream order
  bf16_t* h2   = h1;     // h1 dead after QKV GEMM
  bf16_t* gbuf = qkQK;   // qkQK/vTg dead after attn, attnO dead after o-proj
  if (off > ws_size) return;  // ~136 MB required

  const dim3 tb(32, 8);
  tcast_kernel<<<dim3(96, 32), tb, 0, stream>>>(Wqkv, WqkvT, 1024, 3072);
  tcast_kernel<<<dim3(32, 32), tb, 0, stream>>>(Wo, WoT, 1024, 1024);
  tcast_kernel<<<dim3(128, 32), tb, 0, stream>>>(fc1w, fc1T, 1024, 4096);
  tcast_kernel<<<dim3(32, 128), tb, 0, stream>>>(fc2w, fc2T, 4096, 1024);

  ln_kernel<<<M, 256, 0, stream>>>(x, ln1w, ln1b, h1);

  gemm128b<3><<<dim3(1536), 256, 0, stream>>>(h1, WqkvT, bqkv, nullptr, qkQK, vTg, M, 3072, 1024);

  flash_attn2<<<dim3(32, 64), 256, 0, stream>>>(qkQK, vTg, attnO);

  gemm128b<1><<<dim3(512), 256, 0, stream>>>(attnO, WoT, bo, x, x2, nullptr, M, 1024, 1024);

  ln_kernel<<<M, 256, 0, stream>>>(x2, ln2w, ln2b, h2);

  gemm128b<2><<<dim3(2048), 256, 0, stream>>>(h2, fc1T, fc1b, nullptr, gbuf, nullptr, M, 4096, 1024);

  gemm128b<1><<<dim3(512), 256, 0, stream>>>(gbuf, fc2T, fc2b, x2, (float*)d_out, nullptr, M, 1024, 4096);
}